// Round 1
// baseline (845.605 us; speedup 1.0000x reference)
//
#include <hip/hip_runtime.h>
#include <hip/hip_bf16.h>
#include <cstdint>

#define HID 2048
#define ITR 1024
#define NE 8
#define NTOK 8192
#define BM 128
#define BN 128
#define BK 64
#define MAX_SLOTS 25600   // 16384 + 8*127 padding (<=17400) + 8192 shared, rounded

// ctrl layout (ints)
#define C_COUNTS 0   // [0..7]
#define C_FILL   8   // [8..15]
#define C_PSTART 16  // [16..24] pad_start[0..8]; [24] = shared segment base
#define C_TOTAL  25
#define C_ZEROF  64  // bytes 256.. : zero pad source for gather of invalid rows

typedef __bf16 bf16;
typedef __bf16 bf16x8 __attribute__((ext_vector_type(8)));
typedef float f32x4 __attribute__((ext_vector_type(4)));

typedef const __attribute__((address_space(1))) void* gptr_t;
typedef __attribute__((address_space(3))) void* lptr_t;

__device__ __forceinline__ void gld_lds16(const void* g, void* l) {
  __builtin_amdgcn_global_load_lds((gptr_t)g, (lptr_t)l, 16, 0, 0);
}

// ---------------- conversion kernels ----------------

__global__ void k_cvt_x(const float* __restrict__ in, bf16* __restrict__ out) {
  int i = blockIdx.x * blockDim.x + threadIdx.x;      // each thread: 8 elems
  const float4* p = reinterpret_cast<const float4*>(in) + (size_t)i * 2;
  float4 a = p[0], b = p[1];
  bf16x8 r;
  r[0] = (bf16)a.x; r[1] = (bf16)a.y; r[2] = (bf16)a.z; r[3] = (bf16)a.w;
  r[4] = (bf16)b.x; r[5] = (bf16)b.y; r[6] = (bf16)b.z; r[7] = (bf16)b.w;
  reinterpret_cast<bf16x8*>(out)[i] = r;
}

// in: [R][C] fp32 (z<8 from in8 + z*R*C, z==8 from inS) -> out[z]: [C][R] bf16
__global__ void k_tcvt(const float* __restrict__ in8, const float* __restrict__ inS,
                       bf16* __restrict__ out, int R, int C) {
  int z = blockIdx.z;
  const float* __restrict__ src = (z < 8) ? in8 + (size_t)z * R * C : inS;
  bf16* __restrict__ dst = out + (size_t)z * R * C;
  __shared__ float tile[32][33];
  int c0 = blockIdx.x * 32, r0 = blockIdx.y * 32;
  int tx = threadIdx.x, ty = threadIdx.y;
#pragma unroll
  for (int j = 0; j < 4; ++j)
    tile[ty + j * 8][tx] = src[(size_t)(r0 + ty + j * 8) * C + c0 + tx];
  __syncthreads();
#pragma unroll
  for (int j = 0; j < 4; ++j)
    dst[(size_t)(c0 + ty + j * 8) * R + r0 + tx] = (bf16)tile[tx][ty + j * 8];
}

// ---------------- router ----------------

__global__ void k_router(const float* __restrict__ x, const float* __restrict__ Wr,
                         int* __restrict__ tki, float* __restrict__ tkw,
                         int* __restrict__ ctrl) {
  int lane = threadIdx.x & 63;
  int t = blockIdx.x * 4 + (threadIdx.x >> 6);
  const float4* xr = reinterpret_cast<const float4*>(x + (size_t)t * HID);
  float acc[NE];
#pragma unroll
  for (int e = 0; e < NE; ++e) acc[e] = 0.f;
  for (int k = lane; k < HID / 4; k += 64) {
    float4 xv = xr[k];
#pragma unroll
    for (int e = 0; e < NE; ++e) {
      float4 wv = reinterpret_cast<const float4*>(Wr + (size_t)e * HID)[k];
      acc[e] += xv.x * wv.x + xv.y * wv.y + xv.z * wv.z + xv.w * wv.w;
    }
  }
#pragma unroll
  for (int off = 32; off; off >>= 1)
#pragma unroll
    for (int e = 0; e < NE; ++e) acc[e] += __shfl_xor(acc[e], off, 64);
  if (lane == 0) {
    int i0 = 0; float v0 = acc[0];
#pragma unroll
    for (int e = 1; e < NE; ++e) if (acc[e] > v0) { v0 = acc[e]; i0 = e; }
    int i1 = -1; float v1 = 0.f;
#pragma unroll
    for (int e = 0; e < NE; ++e) {
      if (e == i0) continue;
      if (i1 < 0 || acc[e] > v1) { v1 = acc[e]; i1 = e; }
    }
    float w1 = expf(v1 - v0);       // v0 >= v1
    float s = 1.f + w1;
    tki[t * 2] = i0; tki[t * 2 + 1] = i1;
    tkw[t * 2] = 1.f / s; tkw[t * 2 + 1] = w1 / s;
    atomicAdd(&ctrl[C_COUNTS + i0], 1);
    atomicAdd(&ctrl[C_COUNTS + i1], 1);
  }
}

// ---------------- slot construction ----------------

__global__ void k_setup(int* __restrict__ ctrl, int* __restrict__ stok, float* __restrict__ sw) {
  __shared__ int ps[9];
  if (threadIdx.x == 0) {
    int run = 0;
    for (int e = 0; e < NE; ++e) {
      ctrl[C_PSTART + e] = run; ps[e] = run;
      run += (ctrl[C_COUNTS + e] + 127) & ~127;
    }
    ctrl[C_PSTART + 8] = run; ps[8] = run;
    ctrl[C_TOTAL] = run + NTOK;
  }
  __syncthreads();
  for (int e = 0; e < NE; ++e) {
    int cnt = ctrl[C_COUNTS + e];
    int padded = (cnt + 127) & ~127;
    int base = ps[e];
    for (int i = cnt + threadIdx.x; i < padded; i += blockDim.x) {
      stok[base + i] = -1; sw[base + i] = 0.f;
    }
  }
}

__global__ void k_scatter(const int* __restrict__ tki, const float* __restrict__ tkw,
                          int* __restrict__ ctrl, int* __restrict__ stok, float* __restrict__ sw) {
  int t = blockIdx.x * blockDim.x + threadIdx.x;
  if (t >= NTOK) return;
  int sb = ctrl[C_PSTART + 8];           // shared-expert segment
  stok[sb + t] = t; sw[sb + t] = 1.0f;
#pragma unroll
  for (int k = 0; k < 2; ++k) {
    int e = tki[t * 2 + k];
    int pos = atomicAdd(&ctrl[C_FILL + e], 1);
    int s = ctrl[C_PSTART + e] + pos;
    stok[s] = t; sw[s] = tkw[t * 2 + k];
  }
}

// ---------------- fused gate+up GEMM ----------------
// A: gathered Xbf rows [slot][K=HID]; B: Wgt/Wut [9][ITR][HID] (pre-transposed, row=n, K contiguous)
// out: hbuf[slot][ITR] = w * silu(g) * u   (bf16)

__launch_bounds__(256, 2)
__global__ void k_gateup(const bf16* __restrict__ Xbf,
                         const bf16* __restrict__ Wgt,
                         const bf16* __restrict__ Wut,
                         const int* __restrict__ stok_g,
                         const float* __restrict__ sw_g,
                         const int* __restrict__ ctrl,
                         bf16* __restrict__ hbuf) {
  __shared__ __align__(16) bf16 As[BM * BK];
  __shared__ __align__(16) bf16 Bgs[BN * BK];
  __shared__ __align__(16) bf16 Bus[BN * BK];
  __shared__ int stok[BM];
  __shared__ float swv[BM];

  const int total = ctrl[C_TOTAL];
  const int mt = blockIdx.y;
  const int sbase = mt * BM;
  if (sbase >= total) return;
  const int nt = blockIdx.x;

  int e;
  {
    const int shb = ctrl[C_PSTART + 8];
    if (sbase >= shb) e = 8;
    else { e = 0; while (e < 7 && ctrl[C_PSTART + e + 1] <= sbase) ++e; }
  }
  const bf16* __restrict__ Bg = Wgt + (size_t)e * ITR * HID;
  const bf16* __restrict__ Bu = Wut + (size_t)e * ITR * HID;
  const bf16* zerop = (const bf16*)(ctrl + C_ZEROF);

  const int tid = threadIdx.x;
  if (tid < BM) { stok[tid] = stok_g[sbase + tid]; swv[tid] = sw_g[sbase + tid]; }
  __syncthreads();

  const int lane = tid & 63;
  const int w = tid >> 6;
  const int wr = w >> 1, wc = w & 1;

  // staging precompute: issue j covers LDS rows (j*4+w)*8 .. +7, this lane -> row rj, 16B block bj
  int rj[4], bj[4];
  const bf16* baseA[4];
  bool okA[4];
#pragma unroll
  for (int j = 0; j < 4; ++j) {
    rj[j] = (j * 4 + w) * 8 + (lane >> 3);
    bj[j] = (lane & 7) ^ (rj[j] & 7);          // pre-swizzled global source block
    int tk = stok[rj[j]];
    okA[j] = (tk >= 0);
    baseA[j] = Xbf + (size_t)(tk < 0 ? 0 : tk) * HID + bj[j] * 8;
  }

  f32x4 accg[4][4], accu[4][4];
#pragma unroll
  for (int m = 0; m < 4; ++m)
#pragma unroll
    for (int n = 0; n < 4; ++n) {
      accg[m][n] = f32x4{0.f, 0.f, 0.f, 0.f};
      accu[m][n] = f32x4{0.f, 0.f, 0.f, 0.f};
    }

  const int fr = lane & 15;
  const int kg = lane >> 4;
  const int rA0 = wr * 64 + fr;
  const int rB0 = wc * 64 + fr;
  const int sxz = fr & 7;                       // read-side swizzle (row&7)

  for (int kt = 0; kt < HID / BK; ++kt) {       // 32 K-steps
    const int kofs = kt * BK;
    __syncthreads();                            // previous reads done before overwrite
#pragma unroll
    for (int j = 0; j < 4; ++j) {
      const bf16* sA = okA[j] ? (baseA[j] + kofs) : zerop;
      gld_lds16(sA, (char*)As + (j * 4 + w) * 1024);
      const size_t bo = (size_t)(nt * BN + rj[j]) * HID + kofs + bj[j] * 8;
      gld_lds16(Bg + bo, (char*)Bgs + (j * 4 + w) * 1024);
      gld_lds16(Bu + bo, (char*)Bus + (j * 4 + w) * 1024);
    }
    __syncthreads();                            // drains vmcnt (compiler) + visibility
#pragma unroll
    for (int kc = 0; kc < 2; ++kc) {
      const int pa = ((kg + 4 * kc) ^ sxz) * 8;
      bf16x8 av[4], gv[4], uv[4];
#pragma unroll
      for (int m = 0; m < 4; ++m) {
        av[m] = *reinterpret_cast<const bf16x8*>(As + (rA0 + m * 16) * BK + pa);
        gv[m] = *reinterpret_cast<const bf16x8*>(Bgs + (rB0 + m * 16) * BK + pa);
        uv[m] = *reinterpret_cast<const bf16x8*>(Bus + (rB0 + m * 16) * BK + pa);
      }
#pragma unroll
      for (int m = 0; m < 4; ++m)
#pragma unroll
        for (int n = 0; n < 4; ++n) {
          accg[m][n] = __builtin_amdgcn_mfma_f32_16x16x32_bf16(av[m], gv[n], accg[m][n], 0, 0, 0);
          accu[m][n] = __builtin_amdgcn_mfma_f32_16x16x32_bf16(av[m], uv[n], accu[m][n], 0, 0, 0);
        }
    }
  }

  // epilogue: h = w * silu(g) * u
#pragma unroll
  for (int m = 0; m < 4; ++m) {
    const int row = wr * 64 + m * 16 + kg * 4;
#pragma unroll
    for (int n = 0; n < 4; ++n) {
      const int col = nt * BN + wc * 64 + n * 16 + fr;
#pragma unroll
      for (int r = 0; r < 4; ++r) {
        float g = accg[m][n][r];
        float u = accu[m][n][r];
        float val = swv[row + r] * (g / (1.f + expf(-g))) * u;
        hbuf[(size_t)(sbase + row + r) * ITR + col] = (bf16)val;
      }
    }
  }
}

// ---------------- down GEMM + scatter-add ----------------
// A: hbuf[slot][K=ITR]; B: Wdt [9][HID][ITR]; out[token][HID] += acc

__launch_bounds__(256, 2)
__global__ void k_down(const bf16* __restrict__ hbuf,
                       const bf16* __restrict__ Wdt,
                       const int* __restrict__ stok_g,
                       const int* __restrict__ ctrl,
                       float* __restrict__ out) {
  __shared__ __align__(16) bf16 As[BM * BK];
  __shared__ __align__(16) bf16 Bs[BN * BK];
  __shared__ int stok[BM];

  const int total = ctrl[C_TOTAL];
  const int mt = blockIdx.y;
  const int sbase = mt * BM;
  if (sbase >= total) return;
  const int nt = blockIdx.x;

  int e;
  {
    const int shb = ctrl[C_PSTART + 8];
    if (sbase >= shb) e = 8;
    else { e = 0; while (e < 7 && ctrl[C_PSTART + e + 1] <= sbase) ++e; }
  }
  const bf16* __restrict__ Bd = Wdt + (size_t)e * HID * ITR;

  const int tid = threadIdx.x;
  if (tid < BM) stok[tid] = stok_g[sbase + tid];
  __syncthreads();

  const int lane = tid & 63;
  const int w = tid >> 6;
  const int wr = w >> 1, wc = w & 1;

  int rj[4], bj[4];
#pragma unroll
  for (int j = 0; j < 4; ++j) {
    rj[j] = (j * 4 + w) * 8 + (lane >> 3);
    bj[j] = (lane & 7) ^ (rj[j] & 7);
  }

  f32x4 acc[4][4];
#pragma unroll
  for (int m = 0; m < 4; ++m)
#pragma unroll
    for (int n = 0; n < 4; ++n) acc[m][n] = f32x4{0.f, 0.f, 0.f, 0.f};

  const int fr = lane & 15;
  const int kg = lane >> 4;
  const int rA0 = wr * 64 + fr;
  const int rB0 = wc * 64 + fr;
  const int sxz = fr & 7;

  for (int kt = 0; kt < ITR / BK; ++kt) {       // 16 K-steps
    const int kofs = kt * BK;
    __syncthreads();
#pragma unroll
    for (int j = 0; j < 4; ++j) {
      gld_lds16(hbuf + (size_t)(sbase + rj[j]) * ITR + kofs + bj[j] * 8,
                (char*)As + (j * 4 + w) * 1024);
      gld_lds16(Bd + (size_t)(nt * BN + rj[j]) * ITR + kofs + bj[j] * 8,
                (char*)Bs + (j * 4 + w) * 1024);
    }
    __syncthreads();
#pragma unroll
    for (int kc = 0; kc < 2; ++kc) {
      const int pa = ((kg + 4 * kc) ^ sxz) * 8;
      bf16x8 av[4], bv[4];
#pragma unroll
      for (int m = 0; m < 4; ++m) {
        av[m] = *reinterpret_cast<const bf16x8*>(As + (rA0 + m * 16) * BK + pa);
        bv[m] = *reinterpret_cast<const bf16x8*>(Bs + (rB0 + m * 16) * BK + pa);
      }
#pragma unroll
      for (int m = 0; m < 4; ++m)
#pragma unroll
        for (int n = 0; n < 4; ++n)
          acc[m][n] = __builtin_amdgcn_mfma_f32_16x16x32_bf16(av[m], bv[n], acc[m][n], 0, 0, 0);
    }
  }

#pragma unroll
  for (int m = 0; m < 4; ++m) {
    const int row = wr * 64 + m * 16 + kg * 4;
#pragma unroll
    for (int r = 0; r < 4; ++r) {
      const int tk = stok[row + r];
      if (tk < 0) continue;
#pragma unroll
      for (int n = 0; n < 4; ++n) {
        const int col = nt * BN + wc * 64 + n * 16 + fr;
        atomicAdd(&out[(size_t)tk * HID + col], acc[m][n][r]);
      }
    }
  }
}

// ---------------- launch ----------------

extern "C" void kernel_launch(void* const* d_in, const int* in_sizes, int n_in,
                              void* d_out, int out_size, void* d_ws, size_t ws_size,
                              hipStream_t stream) {
  const float* x    = (const float*)d_in[0];
  const float* Wr   = (const float*)d_in[1];
  const float* Wg   = (const float*)d_in[2];
  const float* Wu   = (const float*)d_in[3];
  const float* Wd   = (const float*)d_in[4];
  const float* Wg_s = (const float*)d_in[5];
  const float* Wu_s = (const float*)d_in[6];
  const float* Wd_s = (const float*)d_in[7];
  float* out = (float*)d_out;

  char* ws = (char*)d_ws;
  size_t off = 0;
  auto alloc = [&](size_t b) { char* p = ws + off; off += (b + 255) & ~(size_t)255; return p; };
  bf16* Xbf  = (bf16*)alloc((size_t)NTOK * HID * 2);
  bf16* Wgt  = (bf16*)alloc((size_t)9 * ITR * HID * 2);
  bf16* Wut  = (bf16*)alloc((size_t)9 * ITR * HID * 2);
  bf16* Wdt  = (bf16*)alloc((size_t)9 * HID * ITR * 2);
  bf16* hbuf = (bf16*)alloc((size_t)MAX_SLOTS * ITR * 2);
  int*   stok = (int*)alloc((size_t)MAX_SLOTS * 4);
  float* sw   = (float*)alloc((size_t)MAX_SLOTS * 4);
  int*   tki  = (int*)alloc((size_t)NTOK * 2 * 4);
  float* tkw  = (float*)alloc((size_t)NTOK * 2 * 4);
  int*   ctrl = (int*)alloc(2048);

  hipMemsetAsync(ctrl, 0, 2048, stream);
  hipMemsetAsync(out, 0, (size_t)NTOK * HID * 4, stream);

  k_cvt_x<<<dim3(NTOK * HID / 8 / 256), dim3(256), 0, stream>>>(x, Xbf);
  k_tcvt<<<dim3(ITR / 32, HID / 32, 9), dim3(32, 8), 0, stream>>>(Wg, Wg_s, Wgt, HID, ITR);
  k_tcvt<<<dim3(ITR / 32, HID / 32, 9), dim3(32, 8), 0, stream>>>(Wu, Wu_s, Wut, HID, ITR);
  k_tcvt<<<dim3(HID / 32, ITR / 32, 9), dim3(32, 8), 0, stream>>>(Wd, Wd_s, Wdt, ITR, HID);
  k_router<<<dim3(NTOK / 4), dim3(256), 0, stream>>>(x, Wr, tki, tkw, ctrl);
  k_setup<<<dim3(1), dim3(256), 0, stream>>>(ctrl, stok, sw);
  k_scatter<<<dim3(NTOK / 256), dim3(256), 0, stream>>>(tki, tkw, ctrl, stok, sw);
  k_gateup<<<dim3(ITR / BN, MAX_SLOTS / BM), dim3(256), 0, stream>>>(Xbf, Wgt, Wut, stok, sw, ctrl, hbuf);
  k_down<<<dim3(HID / BN, MAX_SLOTS / BM), dim3(256), 0, stream>>>(hbuf, Wdt, stok, ctrl, out);
}

// Round 2
// 727.305 us; speedup vs baseline: 1.1627x; 1.1627x over previous
//
#include <hip/hip_runtime.h>
#include <hip/hip_bf16.h>
#include <cstdint>

#define HID 2048
#define ITR 1024
#define NE 8
#define NTOK 8192
#define BM 128
#define BN 128
#define BK 64
#define MAX_SLOTS 25600   // 16384 + 8*127 padding + 8192 shared, rounded

// ctrl layout (ints)
#define C_COUNTS 0   // [0..7]
#define C_FILL   8   // [8..15]
#define C_PSTART 16  // [16..24] pad_start[0..8]; [24] = shared segment base
#define C_TOTAL  25
#define C_ZEROF  64  // bytes 256.. : zero pad source for gather of invalid rows

typedef __bf16 bf16;
typedef __bf16 bf16x4 __attribute__((ext_vector_type(4)));
typedef __bf16 bf16x8 __attribute__((ext_vector_type(8)));
typedef float f32x4 __attribute__((ext_vector_type(4)));

typedef const __attribute__((address_space(1))) void* gptr_t;
typedef __attribute__((address_space(3))) void* lptr_t;

__device__ __forceinline__ void gld_lds16(const void* g, void* l) {
  __builtin_amdgcn_global_load_lds((gptr_t)g, (lptr_t)l, 16, 0, 0);
}

// ---------------- weight transpose+convert ----------------
// in: [R][C] fp32 (z<8 from in8 + z*R*C, z==8 from inS) -> out[z]: [C][R] bf16
__global__ void k_tcvt2(const float* __restrict__ in8, const float* __restrict__ inS,
                        bf16* __restrict__ out, int R, int C) {
  int z = blockIdx.z;
  const float* __restrict__ src = (z < 8) ? in8 + (size_t)z * R * C : inS;
  bf16* __restrict__ dst = out + (size_t)z * R * C;
  __shared__ float tile[64][65];
  int c0 = blockIdx.x * 64, r0 = blockIdx.y * 64;
  int tid = threadIdx.x;
  int rr = tid >> 4, cc = (tid & 15) * 4;
#pragma unroll
  for (int j = 0; j < 4; ++j) {
    float4 v = *reinterpret_cast<const float4*>(&src[(size_t)(r0 + rr + j * 16) * C + c0 + cc]);
    tile[rr + j * 16][cc + 0] = v.x;
    tile[rr + j * 16][cc + 1] = v.y;
    tile[rr + j * 16][cc + 2] = v.z;
    tile[rr + j * 16][cc + 3] = v.w;
  }
  __syncthreads();
#pragma unroll
  for (int j = 0; j < 2; ++j) {
    int s = tid + j * 256;
    int oc = s >> 3, seg = s & 7;
    bf16x8 r;
#pragma unroll
    for (int i = 0; i < 8; ++i) r[i] = (bf16)tile[seg * 8 + i][oc];
    *reinterpret_cast<bf16x8*>(&dst[(size_t)(c0 + oc) * R + r0 + seg * 8]) = r;
  }
}

// ---------------- router (+ fused X fp32->bf16 conversion) ----------------

__global__ void k_router(const float* __restrict__ x, const float* __restrict__ Wr,
                         bf16* __restrict__ Xbf,
                         int* __restrict__ tki, float* __restrict__ tkw,
                         int* __restrict__ ctrl) {
  int lane = threadIdx.x & 63;
  int t = blockIdx.x * 4 + (threadIdx.x >> 6);
  const float4* xr = reinterpret_cast<const float4*>(x + (size_t)t * HID);
  bf16x4* xw = reinterpret_cast<bf16x4*>(Xbf + (size_t)t * HID);
  float acc[NE];
#pragma unroll
  for (int e = 0; e < NE; ++e) acc[e] = 0.f;
  for (int k = lane; k < HID / 4; k += 64) {
    float4 xv = xr[k];
    bf16x4 xb;
    xb[0] = (bf16)xv.x; xb[1] = (bf16)xv.y; xb[2] = (bf16)xv.z; xb[3] = (bf16)xv.w;
    xw[k] = xb;
#pragma unroll
    for (int e = 0; e < NE; ++e) {
      float4 wv = reinterpret_cast<const float4*>(Wr + (size_t)e * HID)[k];
      acc[e] += xv.x * wv.x + xv.y * wv.y + xv.z * wv.z + xv.w * wv.w;
    }
  }
#pragma unroll
  for (int off = 32; off; off >>= 1)
#pragma unroll
    for (int e = 0; e < NE; ++e) acc[e] += __shfl_xor(acc[e], off, 64);
  if (lane == 0) {
    int i0 = 0; float v0 = acc[0];
#pragma unroll
    for (int e = 1; e < NE; ++e) if (acc[e] > v0) { v0 = acc[e]; i0 = e; }
    int i1 = -1; float v1 = 0.f;
#pragma unroll
    for (int e = 0; e < NE; ++e) {
      if (e == i0) continue;
      if (i1 < 0 || acc[e] > v1) { v1 = acc[e]; i1 = e; }
    }
    float w1 = expf(v1 - v0);       // v0 >= v1
    float s = 1.f + w1;
    tki[t * 2] = i0; tki[t * 2 + 1] = i1;
    tkw[t * 2] = 1.f / s; tkw[t * 2 + 1] = w1 / s;
    atomicAdd(&ctrl[C_COUNTS + i0], 1);
    atomicAdd(&ctrl[C_COUNTS + i1], 1);
  }
}

// ---------------- slot construction ----------------

__global__ void k_setup(int* __restrict__ ctrl, int* __restrict__ stok, float* __restrict__ sw) {
  __shared__ int ps[9];
  if (threadIdx.x == 0) {
    int run = 0;
    for (int e = 0; e < NE; ++e) {
      ctrl[C_PSTART + e] = run; ps[e] = run;
      run += (ctrl[C_COUNTS + e] + 127) & ~127;
    }
    ctrl[C_PSTART + 8] = run; ps[8] = run;
    ctrl[C_TOTAL] = run + NTOK;
  }
  __syncthreads();
  for (int e = 0; e < NE; ++e) {
    int cnt = ctrl[C_COUNTS + e];
    int padded = (cnt + 127) & ~127;
    int base = ps[e];
    for (int i = cnt + threadIdx.x; i < padded; i += blockDim.x) {
      stok[base + i] = -1; sw[base + i] = 0.f;
    }
  }
}

__global__ void k_scatter(const int* __restrict__ tki, const float* __restrict__ tkw,
                          int* __restrict__ ctrl, int* __restrict__ stok,
                          float* __restrict__ sw, int* __restrict__ tslot) {
  int t = blockIdx.x * blockDim.x + threadIdx.x;
  if (t >= NTOK) return;
  int sb = ctrl[C_PSTART + 8];           // shared-expert segment
  stok[sb + t] = t; sw[sb + t] = 1.0f;
#pragma unroll
  for (int k = 0; k < 2; ++k) {
    int e = tki[t * 2 + k];
    int pos = atomicAdd(&ctrl[C_FILL + e], 1);
    int s = ctrl[C_PSTART + e] + pos;
    stok[s] = t; sw[s] = tkw[t * 2 + k];
    tslot[t * 2 + k] = s;
  }
}

// ---------------- fused gate+up GEMM ----------------
// A: gathered Xbf rows [slot][K=HID]; B: Wgt/Wut [9][ITR][HID] (pre-transposed)
// out: hbuf[slot][ITR] = w * silu(g) * u   (bf16)

__launch_bounds__(256, 2)
__global__ void k_gateup(const bf16* __restrict__ Xbf,
                         const bf16* __restrict__ Wgt,
                         const bf16* __restrict__ Wut,
                         const int* __restrict__ stok_g,
                         const float* __restrict__ sw_g,
                         const int* __restrict__ ctrl,
                         bf16* __restrict__ hbuf) {
  __shared__ __align__(16) bf16 As[BM * BK];
  __shared__ __align__(16) bf16 Bgs[BN * BK];
  __shared__ __align__(16) bf16 Bus[BN * BK];
  __shared__ int stok[BM];
  __shared__ float swv[BM];

  const int total = ctrl[C_TOTAL];
  const int mt = blockIdx.y;
  const int sbase = mt * BM;
  if (sbase >= total) return;
  const int nt = blockIdx.x;

  int e;
  {
    const int shb = ctrl[C_PSTART + 8];
    if (sbase >= shb) e = 8;
    else { e = 0; while (e < 7 && ctrl[C_PSTART + e + 1] <= sbase) ++e; }
  }
  const bf16* __restrict__ Bg = Wgt + (size_t)e * ITR * HID;
  const bf16* __restrict__ Bu = Wut + (size_t)e * ITR * HID;
  const bf16* zerop = (const bf16*)(ctrl + C_ZEROF);

  const int tid = threadIdx.x;
  if (tid < BM) { stok[tid] = stok_g[sbase + tid]; swv[tid] = sw_g[sbase + tid]; }
  __syncthreads();

  const int lane = tid & 63;
  const int w = tid >> 6;
  const int wr = w >> 1, wc = w & 1;

  int rj[4], bj[4];
  const bf16* baseA[4];
  bool okA[4];
#pragma unroll
  for (int j = 0; j < 4; ++j) {
    rj[j] = (j * 4 + w) * 8 + (lane >> 3);
    bj[j] = (lane & 7) ^ (rj[j] & 7);          // pre-swizzled global source block
    int tk = stok[rj[j]];
    okA[j] = (tk >= 0);
    baseA[j] = Xbf + (size_t)(tk < 0 ? 0 : tk) * HID + bj[j] * 8;
  }

  f32x4 accg[4][4], accu[4][4];
#pragma unroll
  for (int m = 0; m < 4; ++m)
#pragma unroll
    for (int n = 0; n < 4; ++n) {
      accg[m][n] = f32x4{0.f, 0.f, 0.f, 0.f};
      accu[m][n] = f32x4{0.f, 0.f, 0.f, 0.f};
    }

  const int fr = lane & 15;
  const int kg = lane >> 4;
  const int rA0 = wr * 64 + fr;
  const int rB0 = wc * 64 + fr;
  const int sxz = fr & 7;

  for (int kt = 0; kt < HID / BK; ++kt) {       // 32 K-steps
    const int kofs = kt * BK;
    __syncthreads();
#pragma unroll
    for (int j = 0; j < 4; ++j) {
      const bf16* sA = okA[j] ? (baseA[j] + kofs) : zerop;
      gld_lds16(sA, (char*)As + (j * 4 + w) * 1024);
      const size_t bo = (size_t)(nt * BN + rj[j]) * HID + kofs + bj[j] * 8;
      gld_lds16(Bg + bo, (char*)Bgs + (j * 4 + w) * 1024);
      gld_lds16(Bu + bo, (char*)Bus + (j * 4 + w) * 1024);
    }
    __syncthreads();
#pragma unroll
    for (int kc = 0; kc < 2; ++kc) {
      const int pa = ((kg + 4 * kc) ^ sxz) * 8;
      bf16x8 av[4], gv[4], uv[4];
#pragma unroll
      for (int m = 0; m < 4; ++m) {
        av[m] = *reinterpret_cast<const bf16x8*>(As + (rA0 + m * 16) * BK + pa);
        gv[m] = *reinterpret_cast<const bf16x8*>(Bgs + (rB0 + m * 16) * BK + pa);
        uv[m] = *reinterpret_cast<const bf16x8*>(Bus + (rB0 + m * 16) * BK + pa);
      }
#pragma unroll
      for (int m = 0; m < 4; ++m)
#pragma unroll
        for (int n = 0; n < 4; ++n) {
          accg[m][n] = __builtin_amdgcn_mfma_f32_16x16x32_bf16(av[m], gv[n], accg[m][n], 0, 0, 0);
          accu[m][n] = __builtin_amdgcn_mfma_f32_16x16x32_bf16(av[m], uv[n], accu[m][n], 0, 0, 0);
        }
    }
  }

#pragma unroll
  for (int m = 0; m < 4; ++m) {
    const int row = wr * 64 + m * 16 + kg * 4;
#pragma unroll
    for (int n = 0; n < 4; ++n) {
      const int col = nt * BN + wc * 64 + n * 16 + fr;
#pragma unroll
      for (int r = 0; r < 4; ++r) {
        float g = accg[m][n][r];
        float u = accu[m][n][r];
        float val = swv[row + r] * (g / (1.f + expf(-g))) * u;
        hbuf[(size_t)(sbase + row + r) * ITR + col] = (bf16)val;
      }
    }
  }
}

// ---------------- down GEMM -> per-slot bf16 rows ----------------
// A: hbuf[slot][K=ITR]; B: Wdt [9][HID][ITR]; dbuf[slot][HID] = acc (bf16)

__launch_bounds__(256, 2)
__global__ void k_down(const bf16* __restrict__ hbuf,
                       const bf16* __restrict__ Wdt,
                       const int* __restrict__ stok_g,
                       const int* __restrict__ ctrl,
                       bf16* __restrict__ dbuf) {
  __shared__ __align__(16) bf16 As[BM * BK];
  __shared__ __align__(16) bf16 Bs[BN * BK];
  __shared__ int stok[BM];

  const int total = ctrl[C_TOTAL];
  const int mt = blockIdx.y;
  const int sbase = mt * BM;
  if (sbase >= total) return;
  const int nt = blockIdx.x;

  int e;
  {
    const int shb = ctrl[C_PSTART + 8];
    if (sbase >= shb) e = 8;
    else { e = 0; while (e < 7 && ctrl[C_PSTART + e + 1] <= sbase) ++e; }
  }
  const bf16* __restrict__ Bd = Wdt + (size_t)e * HID * ITR;

  const int tid = threadIdx.x;
  if (tid < BM) stok[tid] = stok_g[sbase + tid];
  __syncthreads();

  const int lane = tid & 63;
  const int w = tid >> 6;
  const int wr = w >> 1, wc = w & 1;

  int rj[4], bj[4];
#pragma unroll
  for (int j = 0; j < 4; ++j) {
    rj[j] = (j * 4 + w) * 8 + (lane >> 3);
    bj[j] = (lane & 7) ^ (rj[j] & 7);
  }

  f32x4 acc[4][4];
#pragma unroll
  for (int m = 0; m < 4; ++m)
#pragma unroll
    for (int n = 0; n < 4; ++n) acc[m][n] = f32x4{0.f, 0.f, 0.f, 0.f};

  const int fr = lane & 15;
  const int kg = lane >> 4;
  const int rA0 = wr * 64 + fr;
  const int rB0 = wc * 64 + fr;
  const int sxz = fr & 7;

  for (int kt = 0; kt < ITR / BK; ++kt) {       // 16 K-steps
    const int kofs = kt * BK;
    __syncthreads();
#pragma unroll
    for (int j = 0; j < 4; ++j) {
      gld_lds16(hbuf + (size_t)(sbase + rj[j]) * ITR + kofs + bj[j] * 8,
                (char*)As + (j * 4 + w) * 1024);
      gld_lds16(Bd + (size_t)(nt * BN + rj[j]) * ITR + kofs + bj[j] * 8,
                (char*)Bs + (j * 4 + w) * 1024);
    }
    __syncthreads();
#pragma unroll
    for (int kc = 0; kc < 2; ++kc) {
      const int pa = ((kg + 4 * kc) ^ sxz) * 8;
      bf16x8 av[4], bv[4];
#pragma unroll
      for (int m = 0; m < 4; ++m) {
        av[m] = *reinterpret_cast<const bf16x8*>(As + (rA0 + m * 16) * BK + pa);
        bv[m] = *reinterpret_cast<const bf16x8*>(Bs + (rB0 + m * 16) * BK + pa);
      }
#pragma unroll
      for (int m = 0; m < 4; ++m)
#pragma unroll
        for (int n = 0; n < 4; ++n)
          acc[m][n] = __builtin_amdgcn_mfma_f32_16x16x32_bf16(av[m], bv[n], acc[m][n], 0, 0, 0);
    }
  }

#pragma unroll
  for (int m = 0; m < 4; ++m) {
    const int row = wr * 64 + m * 16 + kg * 4;
#pragma unroll
    for (int r = 0; r < 4; ++r) {
      if (stok[row + r] < 0) continue;          // pad slot: never read
#pragma unroll
      for (int n = 0; n < 4; ++n) {
        const int col = nt * BN + wc * 64 + n * 16 + fr;
        dbuf[(size_t)(sbase + row + r) * HID + col] = (bf16)acc[m][n][r];
      }
    }
  }
}

// ---------------- combine: out[t] = dbuf[shared(t)] + dbuf[s0] + dbuf[s1] ----------------

__global__ void k_combine(const bf16* __restrict__ dbuf, const int* __restrict__ tslot,
                          const int* __restrict__ ctrl, float* __restrict__ out) {
  const int t = blockIdx.x;
  const int sb = ctrl[C_PSTART + 8];
  const int s0 = tslot[t * 2], s1 = tslot[t * 2 + 1];
  const int c = threadIdx.x * 8;
  bf16x8 a = *reinterpret_cast<const bf16x8*>(&dbuf[(size_t)(sb + t) * HID + c]);
  bf16x8 b = *reinterpret_cast<const bf16x8*>(&dbuf[(size_t)s0 * HID + c]);
  bf16x8 d = *reinterpret_cast<const bf16x8*>(&dbuf[(size_t)s1 * HID + c]);
  float r[8];
#pragma unroll
  for (int i = 0; i < 8; ++i) r[i] = (float)a[i] + (float)b[i] + (float)d[i];
  float4* o = reinterpret_cast<float4*>(&out[(size_t)t * HID + c]);
  o[0] = float4{r[0], r[1], r[2], r[3]};
  o[1] = float4{r[4], r[5], r[6], r[7]};
}

// ---------------- launch ----------------

extern "C" void kernel_launch(void* const* d_in, const int* in_sizes, int n_in,
                              void* d_out, int out_size, void* d_ws, size_t ws_size,
                              hipStream_t stream) {
  const float* x    = (const float*)d_in[0];
  const float* Wr   = (const float*)d_in[1];
  const float* Wg   = (const float*)d_in[2];
  const float* Wu   = (const float*)d_in[3];
  const float* Wd   = (const float*)d_in[4];
  const float* Wg_s = (const float*)d_in[5];
  const float* Wu_s = (const float*)d_in[6];
  const float* Wd_s = (const float*)d_in[7];
  float* out = (float*)d_out;

  char* ws = (char*)d_ws;
  size_t off = 0;
  auto alloc = [&](size_t b) { char* p = ws + off; off += (b + 255) & ~(size_t)255; return p; };
  bf16* Xbf  = (bf16*)alloc((size_t)NTOK * HID * 2);        // 33.5 MB
  bf16* Wgt  = (bf16*)alloc((size_t)9 * ITR * HID * 2);     // 37.7 MB
  bf16* Wut  = (bf16*)alloc((size_t)9 * ITR * HID * 2);     // 37.7 MB
  bf16* Wdt  = (bf16*)alloc((size_t)9 * HID * ITR * 2);     // 37.7 MB
  bf16* hbuf = (bf16*)alloc((size_t)MAX_SLOTS * ITR * 2);   // 52.4 MB
  int*   stok = (int*)alloc((size_t)MAX_SLOTS * 4);
  float* sw   = (float*)alloc((size_t)MAX_SLOTS * 4);
  int*   tki  = (int*)alloc((size_t)NTOK * 2 * 4);
  float* tkw  = (float*)alloc((size_t)NTOK * 2 * 4);
  int*   tslot= (int*)alloc((size_t)NTOK * 2 * 4);
  int*   ctrl = (int*)alloc(2048);

  // dbuf (104.9 MB) aliases Xbf+Wgt+Wut (109 MB): all three are dead once
  // k_gateup finishes, and k_down/k_combine are the only users of dbuf.
  bf16* dbuf = (bf16*)Xbf;

  hipMemsetAsync(ctrl, 0, 2048, stream);

  k_tcvt2<<<dim3(ITR / 64, HID / 64, 9), dim3(256), 0, stream>>>(Wg, Wg_s, Wgt, HID, ITR);
  k_tcvt2<<<dim3(ITR / 64, HID / 64, 9), dim3(256), 0, stream>>>(Wu, Wu_s, Wut, HID, ITR);
  k_tcvt2<<<dim3(HID / 64, ITR / 64, 9), dim3(256), 0, stream>>>(Wd, Wd_s, Wdt, ITR, HID);
  k_router<<<dim3(NTOK / 4), dim3(256), 0, stream>>>(x, Wr, Xbf, tki, tkw, ctrl);
  k_setup<<<dim3(1), dim3(256), 0, stream>>>(ctrl, stok, sw);
  k_scatter<<<dim3(NTOK / 256), dim3(256), 0, stream>>>(tki, tkw, ctrl, stok, sw, tslot);
  k_gateup<<<dim3(ITR / BN, MAX_SLOTS / BM), dim3(256), 0, stream>>>(Xbf, Wgt, Wut, stok, sw, ctrl, hbuf);
  k_down<<<dim3(HID / BN, MAX_SLOTS / BM), dim3(256), 0, stream>>>(hbuf, Wdt, stok, ctrl, dbuf);
  k_combine<<<dim3(NTOK), dim3(256), 0, stream>>>(dbuf, tslot, ctrl, out);
}